// Round 8
// baseline (307527.490 us; speedup 1.0000x reference)
//
#include <hip/hip_runtime.h>
#include <math.h>

// ---------------------------------------------------------------------------
// Persistent-kernel trainer for the 16384-step sequential MLP scan.
// WG g owns w1 rows-slice cols [4g,4g+4) (row-major), w2 cols [4g,4g+4),
// w3 rows [4g,4g+4) in LDS. Cross-WG via agent-scope relaxed atomics (MALL).
// R8: funnel barriers -> producer-count flag sync (one MALL hop): 16 P-counters
// gate the P3 exchange, 16 Q-counters gate the O1R/U/AC exchange. Producer
// drains vmcnt then bumps its bank counter; consumers poll 16 counters for
// 16*(t+1). W1 update+u stays in the P shadow. O1R banks 8->16.
// ---------------------------------------------------------------------------

#define NSTEP 16384
#define INDIM 1024
#define HID   1024
#define OUTD  64
#define LR    0.01f
#define EPSN  1e-8f

#define NWG   256
#define TPB   1024
#define CW    4

// workspace layout (float indices)
#define OFF_ARRIVE   0                         // 256 ints (init barrier)
#define OFF_RELEASE  512                       // 1 int
#define OFF_PCNT     640                       // 16 ints
#define OFF_QCNT     704                       // 16 ints
#define OFF_U        1024                      // HID
#define OFF_O1R      2048                      // 2*16*HID
#define OFF_P3       (OFF_O1R + 2*16*HID)      // 2*16*64
#define OFF_ACC      (OFF_P3 + 2*16*64)        // 2*16*8
#define OFF_SDOT     (OFF_ACC + 2*16*8)        // NSTEP
#define OFF_NORMX    (OFF_SDOT + NSTEP)        // NSTEP

// ACC slots: 0 m1, 1 m2, 2 m3, 3 dot_d2o2, 4 sum_o2sq, 5 sum_B2sq, 6 sum_a2sq

__device__ __forceinline__ float dload(const float* p){
  return __hip_atomic_load(p, __ATOMIC_RELAXED, __HIP_MEMORY_SCOPE_AGENT);
}
__device__ __forceinline__ void dstore(float* p, float v){
  __hip_atomic_store(p, v, __ATOMIC_RELAXED, __HIP_MEMORY_SCOPE_AGENT);
}
__device__ __forceinline__ int rload(const int* p){
  return __hip_atomic_load(p, __ATOMIC_RELAXED, __HIP_MEMORY_SCOPE_AGENT);
}
__device__ __forceinline__ void rstore(int* p, int v){
  __hip_atomic_store(p, v, __ATOMIC_RELAXED, __HIP_MEMORY_SCOPE_AGENT);
}
__device__ __forceinline__ void iadd(int* p){
  __hip_atomic_fetch_add(p, 1, __ATOMIC_RELAXED, __HIP_MEMORY_SCOPE_AGENT);
}
__device__ __forceinline__ float wredf(float v){
  #pragma unroll
  for (int m = 32; m; m >>= 1) v += __shfl_xor(v, m, 64);
  return v;
}
__device__ __forceinline__ float sigf(float z){ return 1.f/(1.f+__expf(-z)); }

__global__ __launch_bounds__(64) void bp_init(const float* __restrict__ x, float* wsf){
  const int t = blockIdx.x, tid = threadIdx.x;
  const float* xt = x + (size_t)t * INDIM;
  const float* xp = x + (size_t)(t > 0 ? t - 1 : 0) * INDIM;
  float sp = 0.f, nx = 0.f;
  #pragma unroll
  for (int e = 0; e < INDIM/64; e++){
    int i = tid + 64*e; float a = xt[i];
    nx += a*a; sp += a*xp[i];
  }
  sp = wredf(sp); nx = wredf(nx);
  if (tid == 0){ wsf[OFF_SDOT + t] = (t > 0) ? sp : 0.f; wsf[OFF_NORMX + t] = nx; }
  if (blockIdx.x == 0){
    int* wsi = (int*)wsf;
    for (int i = tid; i < 256; i += 64) wsi[OFF_ARRIVE + i] = 0;
    if (tid == 0) wsi[OFF_RELEASE] = 0;
    if (tid < 16){ wsi[OFF_PCNT + tid] = 0; wsi[OFF_QCNT + tid] = 0; }
    for (int i = tid; i < 2*16*HID; i += 64) wsf[OFF_O1R + i] = 0.f;
    for (int i = tid; i < 2*16*64;  i += 64) wsf[OFF_P3 + i]  = 0.f;
    for (int i = tid; i < 2*16*8;   i += 64) wsf[OFF_ACC + i] = 0.f;
    __syncthreads();
    if (tid == 0){
      float* acc1 = wsf + OFF_ACC + 16*8;
      acc1[0] = 1.f; acc1[1] = 1.f; acc1[2] = 1.f; acc1[5] = 1.f;
    }
  }
}

__global__ __launch_bounds__(TPB) void bp_train(
    const float* __restrict__ xdat, const float* __restrict__ tgt,
    const float* __restrict__ w1g, const float* __restrict__ b1g,
    const float* __restrict__ w2g, const float* __restrict__ b2g,
    const float* __restrict__ w3g, const float* __restrict__ b3g,
    float* __restrict__ out, float* wsf)
{
  alignas(16) __shared__ float s1r[HID*CW];   // w1 ROW-major: [i][j]
  alignas(16) __shared__ float s2[CW*HID];    // w2 col-major: [j][i]
  __shared__ float s3[CW*OUTD];               // w3 rows
  alignas(16) __shared__ float a1b[2][HID];
  __shared__ float d1s[HID];
  __shared__ float b1s[HID];
  __shared__ float o1f[HID];
  __shared__ float d3b[2][OUTD];
  __shared__ float p3r[OUTD];
  __shared__ float b3s[OUTD];
  __shared__ float o2l[CW], d2l[CW], b2l[CW];
  __shared__ float a2b[2][CW];
  __shared__ float ascr[256];

  const int tid = threadIdx.x;
  const int wg  = blockIdx.x;
  int*   arrive  = (int*)wsf + OFF_ARRIVE;
  int*   release = (int*)wsf + OFF_RELEASE;
  int*   PCNT    = (int*)wsf + OFF_PCNT;
  int*   QCNT    = (int*)wsf + OFF_QCNT;
  float* U   = wsf + OFF_U;
  float* O1R = wsf + OFF_O1R;
  float* P3  = wsf + OFF_P3;
  float* AC  = wsf + OFF_ACC;
  float* SD  = wsf + OFF_SDOT;
  float* NX  = wsf + OFF_NORMX;
  const int bank = wg & 15;
  const int wid  = tid >> 6;

  // ---- load owned slices + replicas, zero state ----
  {
    const float4 wv = *reinterpret_cast<const float4*>(&w1g[(size_t)tid*HID + wg*CW]);
    *reinterpret_cast<float4*>(&s1r[4*tid]) = wv;
  }
  for (int v = tid; v < CW*HID; v += TPB){
    int j = v & (CW-1); int i = v >> 2;
    s2[j*HID + i] = w2g[(size_t)i*HID + wg*CW + j];
  }
  if (tid < CW*OUTD){
    int i = tid >> 6; int k = tid & 63;
    s3[tid] = w3g[(size_t)(wg*CW + i)*OUTD + k];
  }
  b1s[tid] = b1g[tid]; d1s[tid] = 0.f; o1f[tid] = 0.f; a1b[1][tid] = 0.f;
  if (tid < OUTD){ b3s[tid] = b3g[tid]; d3b[1][tid] = 0.f; p3r[tid] = 0.f; }
  if (tid < CW){
    b2l[tid] = b2g[wg*CW + tid];
    o2l[tid] = 0.f; d2l[tid] = 0.f; a2b[0][tid] = 0.f; a2b[1][tid] = 0.f;
  }
  __syncthreads();

  // ---- publish u for step 0 ----
  {
    float xv = xdat[tid];
    float4 w = *reinterpret_cast<const float4*>(&s1r[4*tid]);
    float u0_ = wredf(xv*w.x), u1_ = wredf(xv*w.y);
    float u2_ = wredf(xv*w.z), u3_ = wredf(xv*w.w);
    if ((tid & 63) == 0){
      ascr[wid*4+0]=u0_; ascr[wid*4+1]=u1_; ascr[wid*4+2]=u2_; ascr[wid*4+3]=u3_;
    }
    __syncthreads();
    if (tid < CW){
      float s = 0.f;
      for (int w2_ = 0; w2_ < 16; w2_++) s += ascr[w2_*4 + tid];
      dstore(&U[wg*CW + tid], s);
    }
  }
  // initial full funnel barrier (once)
  {
    asm volatile("s_waitcnt vmcnt(0) lgkmcnt(0)" ::: "memory");
    __syncthreads();
    if (tid == 0) rstore(&arrive[wg], 1);
    if (wg == 0){
      if (tid < NWG){ while (rload(&arrive[tid]) < 1) __builtin_amdgcn_s_sleep(1); }
      __syncthreads();
      if (tid == 0) rstore(release, 1);
    }
    if (tid == 0){ while (rload(release) < 1) __builtin_amdgcn_s_sleep(1); }
    __syncthreads();
    asm volatile("" ::: "memory");
  }

  for (int t = 0; t <= NSTEP; t++){
    const int p = t & 1, qq = p ^ 1;
    float* a1c = a1b[p];  float* a1p = a1b[qq];
    float* a2c = a2b[p];  float* a2p = a2b[qq];
    float* d3c = d3b[p];  float* d3p = d3b[qq];

    // ================= Phase A =================
    if (tid < 112){
      int s = tid >> 4, b = tid & 15;
      ascr[128 + s*16 + b] = dload(&AC[(qq*16 + b)*8 + s]);
    }
    float u0 = dload(&U[tid]);
    float r0 = 0.f;
    #pragma unroll
    for (int b = 0; b < 16; b++)
      r0 += dload(&O1R[(qq*16 + b)*HID + tid]);
    float a1p0 = a1p[tid];
    float of0 = r0 * a1p0 * (1.f - a1p0);
    o1f[tid] = of0;

    // stage 2: per-wave partials
    {
      float v0 = d1s[tid]*of0;
      float v1 = of0*of0;
      float Ba = b1s[tid] - LR*of0;
      float v2 = Ba*Ba;
      float v3 = a1p0*a1p0;
      v0 = wredf(v0); v1 = wredf(v1); v2 = wredf(v2); v3 = wredf(v3);
      if ((tid & 63) == 0){
        ascr[0*16+wid]=v0; ascr[1*16+wid]=v1; ascr[2*16+wid]=v2; ascr[3*16+wid]=v3;
      }
      if (tid < 64){
        float d3v = d3p[tid];
        float v4 = d3v*d3v;
        float B3 = b3s[tid] - LR*d3v; float v5 = B3*B3;
        float v6 = d3v * p3r[tid];
        v4 = wredf(v4); v5 = wredf(v5); v6 = wredf(v6);
        if (tid == 0){ ascr[244]=v4; ascr[245]=v5; ascr[246]=v6; }
      }
    }
    __syncthreads();
    if (tid < 64){
      if (tid < 4){
        float s = 0.f;
        #pragma unroll
        for (int w = 0; w < 16; w++) s += ascr[tid*16 + w];
        ascr[240 + tid] = s;
      } else if (tid >= 8 && tid < 15){
        int s_ = tid - 8;
        float s = 0.f;
        #pragma unroll
        for (int b = 0; b < 16; b++) s += ascr[128 + s_*16 + b];
        ascr[248 + s_] = s;
      }
    }
    __syncthreads();
    float dd  = ascr[240], so  = ascr[241], sb  = ascr[242], sa1 = ascr[243];
    float sd3 = ascr[244], sb3 = ascr[245], dp3 = ascr[246];
    float m1p = ascr[248], m2p = ascr[249], m3p = ascr[250], dq  = ascr[251];
    float soq = ascr[252], sB2 = ascr[253], sa2 = ascr[254];

    float nxp = NX[t > 0 ? t - 1 : 0];
    float sdt = SD[t < NSTEP ? t : 0];
    float n1  = fmaxf(sqrtf(fmaxf(m1p - 2.f*LR*dd  + LR*LR*nxp*so,  0.f)), EPSN);
    float nb1 = fmaxf(sqrtf(sb),  EPSN);
    float n2  = fmaxf(sqrtf(fmaxf(m2p - 2.f*LR*dq  + LR*LR*sa1*soq, 0.f)), EPSN);
    float nb2 = fmaxf(sqrtf(sB2), EPSN);
    float n3  = fmaxf(sqrtf(fmaxf(m3p - 2.f*LR*dp3 + LR*LR*sa2*sd3, 0.f)), EPSN);
    float nb3 = fmaxf(sqrtf(sb3), EPSN);
    float rn1 = 1.f/n1, rnb1 = 1.f/nb1, rn2 = 1.f/n2, rnb2 = 1.f/nb2;
    float rn3 = 1.f/n3, rnb3 = 1.f/nb3;

    // stage 3
    {
      float B0 = (b1s[tid] - LR*of0)*rnb1; b1s[tid] = B0;
      float dn0 = (u0 - LR*of0*sdt)*rn1;   d1s[tid] = dn0;
      a1c[tid] = sigf(dn0 + B0);
    }
    __syncthreads();

    // stage 4: fused W2 update + matvec
    {
      int j = tid >> 8, l = tid & 255;
      float coef = LR * o2l[j];
      float4 w  = *reinterpret_cast<float4*>(&s2[j*HID + 4*l]);
      float4 ap = *reinterpret_cast<const float4*>(&a1p[4*l]);
      float4 ac = *reinterpret_cast<const float4*>(&a1c[4*l]);
      w.x = (w.x - coef*ap.x)*rn2;  w.y = (w.y - coef*ap.y)*rn2;
      w.z = (w.z - coef*ap.z)*rn2;  w.w = (w.w - coef*ap.w)*rn2;
      *reinterpret_cast<float4*>(&s2[j*HID + 4*l]) = w;
      float acc = ac.x*w.x + ac.y*w.y + ac.z*w.z + ac.w*w.w;
      float ms  = w.x*w.x + w.y*w.y + w.z*w.z + w.w*w.w;
      acc = wredf(acc); ms = wredf(ms);
      if ((tid & 63) == 0){ ascr[wid] = acc; ascr[16 + wid] = ms; }
    }
    __syncthreads();
    if (tid < CW){
      float d2 = ascr[4*tid] + ascr[4*tid+1] + ascr[4*tid+2] + ascr[4*tid+3];
      d2l[tid] = d2;
      float b2n = (b2l[tid] - LR*o2l[tid])*rnb2;
      b2l[tid] = b2n;
      a2c[tid] = sigf(d2 + b2n);
    }
    __syncthreads();
    if (tid == 0){
      float m2 = 0.f;
      #pragma unroll
      for (int w = 0; w < 16; w++) m2 += ascr[16 + w];
      unsafeAtomicAdd(&AC[(p*16 + bank)*8 + 1], m2);
      float s = 0.f;
      for (int j = 0; j < CW; j++){ float a = a2c[j]; s += a*a; }
      unsafeAtomicAdd(&AC[(p*16 + bank)*8 + 6], s);
    }

    // stage 5: fused W3 update + P3 publish (wave0 only)
    if (tid < OUTD){
      int k = tid;
      float d3k = d3p[k];
      float contrib = 0.f, m3s = 0.f;
      #pragma unroll
      for (int i = 0; i < CW; i++){
        float w = s3[i*OUTD + k];
        w = (w - LR*a2p[i]*d3k)*rn3;
        s3[i*OUTD + k] = w;
        contrib += a2c[i]*w;
        m3s += w*w;
      }
      unsafeAtomicAdd(&P3[(p*16 + bank)*OUTD + k], contrib);
      m3s = wredf(m3s);
      if (k == 0) unsafeAtomicAdd(&AC[(p*16 + bank)*8 + 2], m3s);
      b3s[k] = (b3s[k] - LR*d3k)*rnb3;
    }

    // ===== epilogue =====
    if (t == NSTEP){
      __syncthreads();
      const float* xl = xdat + (size_t)(NSTEP - 1)*INDIM;
      float xv = xl[tid];
      float c0 = LR*o1f[wg*CW+0], c1 = LR*o1f[wg*CW+1];
      float c2 = LR*o1f[wg*CW+2], c3 = LR*o1f[wg*CW+3];
      float4 w = *reinterpret_cast<const float4*>(&s1r[4*tid]);
      float4 ov;
      ov.x = (w.x - c0*xv)*rn1; ov.y = (w.y - c1*xv)*rn1;
      ov.z = (w.z - c2*xv)*rn1; ov.w = (w.w - c3*xv)*rn1;
      *reinterpret_cast<float4*>(&out[(size_t)tid*HID + wg*CW]) = ov;
      float4 o2v;
      o2v.x = s2[0*HID+tid]; o2v.y = s2[1*HID+tid];
      o2v.z = s2[2*HID+tid]; o2v.w = s2[3*HID+tid];
      *reinterpret_cast<float4*>(&out[(size_t)HID*HID + (size_t)tid*HID + wg*CW]) = o2v;
      if (tid < OUTD){
        #pragma unroll
        for (int i = 0; i < CW; i++)
          out[(size_t)2*HID*HID + (size_t)(wg*CW + i)*OUTD + tid] = s3[i*OUTD + tid];
      }
      break;
    }

    // ---- P-arrive: all P-side publishes (stage5 P3, m2/sa2/m3) are wave0's ----
    if (wid == 0){
      asm volatile("s_waitcnt vmcnt(0) lgkmcnt(0)" ::: "memory");
      if (tid == 0) iadd(&PCNT[bank]);
    }

    // ---- shadow (WG-local): fused W1 update + u_{t+1} partials + m1 ----
    float u_pub = 0.f;
    {
      const float* xp_ = xdat + (size_t)(t > 0 ? t - 1 : 0)*INDIM;
      const float* xn_ = xdat + (size_t)(t + 1 < NSTEP ? t + 1 : NSTEP - 1)*INDIM;
      float xpv = xp_[tid], xnv = xn_[tid];
      float c0 = LR*o1f[wg*CW+0], c1 = LR*o1f[wg*CW+1];
      float c2 = LR*o1f[wg*CW+2], c3 = LR*o1f[wg*CW+3];
      float4 w = *reinterpret_cast<float4*>(&s1r[4*tid]);
      w.x = (w.x - c0*xpv)*rn1; w.y = (w.y - c1*xpv)*rn1;
      w.z = (w.z - c2*xpv)*rn1; w.w = (w.w - c3*xpv)*rn1;
      *reinterpret_cast<float4*>(&s1r[4*tid]) = w;
      float m1s = w.x*w.x + w.y*w.y + w.z*w.z + w.w*w.w;
      float u0_ = wredf(xnv*w.x), u1_ = wredf(xnv*w.y);
      float u2_ = wredf(xnv*w.z), u3_ = wredf(xnv*w.w);
      m1s = wredf(m1s);
      if ((tid & 63) == 0){
        ascr[wid*4+0]=u0_; ascr[wid*4+1]=u1_; ascr[wid*4+2]=u2_; ascr[wid*4+3]=u3_;
        ascr[64 + wid] = m1s;
      }
      __syncthreads();
      if (tid < CW){
        float s = 0.f;
        #pragma unroll
        for (int w2_ = 0; w2_ < 16; w2_++) s += ascr[w2_*4 + tid];
        u_pub = s;
      }
      if (tid == 0){
        float m1 = 0.f;
        #pragma unroll
        for (int w2_ = 0; w2_ < 16; w2_++) m1 += ascr[64 + w2_];
        unsafeAtomicAdd(&AC[(p*16 + bank)*8 + 0], m1);
      }
    }

    // ---- P-wait: poll 16 producer counters ----
    {
      const int ptgt = 16*(t+1);
      if (tid < 16){
        while (rload(&PCNT[tid]) < ptgt) __builtin_amdgcn_s_sleep(1);
      }
      __syncthreads();
      asm volatile("" ::: "memory");
    }

    // ================= Phase B =================
    if (tid < CW) dstore(&U[wg*CW + tid], u_pub);   // safe: all WGs past A stage1
    if (tid < OUTD){
      float s = 0.f;
      for (int b = 0; b < 16; b++) s += dload(&P3[(p*16 + b)*OUTD + tid]);
      p3r[tid] = s;
      float a3 = sigf(s + b3s[tid]);
      float e3 = __expf(-a3);
      float es = wredf(e3);
      float net = e3 / es;
      float tv = tgt[(size_t)t*OUTD + tid];
      d3c[tid] = (tv - net) * a3 * (1.f - a3);
    }
    __syncthreads();
    if (tid < CW*OUTD){
      int i = tid >> 6, k = tid & 63;
      float v = wredf(s3[i*OUTD + k] * d3c[k]);
      if (k == 0){ float a2v = a2c[i]; o2l[i] = v * a2v * (1.f - a2v); }
    }
    __syncthreads();
    if (tid == 0){
      float dd2 = 0.f, so2 = 0.f, sB2n = 0.f;
      for (int j = 0; j < CW; j++){
        float ov = o2l[j];
        dd2 += d2l[j]*ov; so2 += ov*ov;
        float B = b2l[j] - LR*ov; sB2n += B*B;
      }
      unsafeAtomicAdd(&AC[(p*16 + bank)*8 + 3], dd2);
      unsafeAtomicAdd(&AC[(p*16 + bank)*8 + 4], so2);
      unsafeAtomicAdd(&AC[(p*16 + bank)*8 + 5], sB2n);
    }
    // o1 banked partial over owned columns
    {
      float q0 = s2[0*HID+tid]*o2l[0] + s2[1*HID+tid]*o2l[1]
               + s2[2*HID+tid]*o2l[2] + s2[3*HID+tid]*o2l[3];
      unsafeAtomicAdd(&O1R[(p*16 + bank)*HID + tid], q0);
    }
    // zero next-parity accumulators
    if (wg < 16) dstore(&O1R[(qq*16 + wg)*HID + tid], 0.f);
    if (wg < 16){
      if (tid < OUTD) dstore(&P3[(qq*16 + wg)*OUTD + tid], 0.f);
      if (tid < 8)    dstore(&AC[(qq*16 + wg)*8 + tid], 0.f);
    }
    // ---- Q-arrive: block-wide drain, then bump ----
    asm volatile("s_waitcnt vmcnt(0) lgkmcnt(0)" ::: "memory");
    __syncthreads();
    if (tid == 0) iadd(&QCNT[bank]);
    // ---- Q-wait ----
    {
      const int qtgt = 16*(t+1);
      if (tid < 16){
        while (rload(&QCNT[tid]) < qtgt) __builtin_amdgcn_s_sleep(1);
      }
      __syncthreads();
      asm volatile("" ::: "memory");
    }
  }
}

extern "C" void kernel_launch(void* const* d_in, const int* in_sizes, int n_in,
                              void* d_out, int out_size, void* d_ws, size_t ws_size,
                              hipStream_t stream){
  const float* x  = (const float*)d_in[0];
  const float* tg = (const float*)d_in[1];
  const float* w1 = (const float*)d_in[2];
  const float* b1 = (const float*)d_in[3];
  const float* w2 = (const float*)d_in[4];
  const float* b2 = (const float*)d_in[5];
  const float* w3 = (const float*)d_in[6];
  const float* b3 = (const float*)d_in[7];
  float* out = (float*)d_out;
  float* wsf = (float*)d_ws;
  hipLaunchKernelGGL(bp_init,  dim3(NSTEP), dim3(64),  0, stream, x, wsf);
  hipLaunchKernelGGL(bp_train, dim3(NWG),   dim3(TPB), 0, stream,
                     x, tg, w1, b1, w2, b2, w3, b3, out, wsf);
}

// Round 9
// 230645.215 us; speedup vs baseline: 1.3333x; 1.3333x over previous
//
#include <hip/hip_runtime.h>
#include <math.h>

// ---------------------------------------------------------------------------
// Persistent-kernel trainer for the 16384-step sequential MLP scan.
// WG g owns w1 rows-slice cols [4g,4g+4) (row-major), w2 cols [4g,4g+4),
// w3 rows [4g,4g+4) in LDS. Cross-WG via agent-scope relaxed atomics (MALL).
// R9: R8's producer-count single-hop sync, but each counter PADDED to its own
// 128B line (R8 regression root-caused: 16 counters in ONE cache line ->
// 4096 poll streams + 256 atomics serialized on one line). O1R back to
// 8 banks (R7-measured). 2 syncs/step, 1 MALL hop each.
// ---------------------------------------------------------------------------

#define NSTEP 16384
#define INDIM 1024
#define HID   1024
#define OUTD  64
#define LR    0.01f
#define EPSN  1e-8f

#define NWG   256
#define TPB   1024
#define CW    4
#define NBANK 8      // O1R banks
#define CSTR  32     // counter stride in ints (128 B)

// workspace layout (float/int indices)
#define OFF_ARRIVE   0                         // 256 ints (init barrier)
#define OFF_RELEASE  512                       // 1 int
#define OFF_PCNT     1024                      // 16 counters, stride 32 ints
#define OFF_QCNT     2048                      // 16 counters, stride 32 ints
#define OFF_U        4096                      // HID floats
#define OFF_O1R      (OFF_U + HID)             // 2*NBANK*HID
#define OFF_P3       (OFF_O1R + 2*NBANK*HID)   // 2*16*64
#define OFF_ACC      (OFF_P3 + 2*16*64)        // 2*16*8
#define OFF_SDOT     (OFF_ACC + 2*16*8)        // NSTEP
#define OFF_NORMX    (OFF_SDOT + NSTEP)        // NSTEP

// ACC slots: 0 m1, 1 m2, 2 m3, 3 dot_d2o2, 4 sum_o2sq, 5 sum_B2sq, 6 sum_a2sq

__device__ __forceinline__ float dload(const float* p){
  return __hip_atomic_load(p, __ATOMIC_RELAXED, __HIP_MEMORY_SCOPE_AGENT);
}
__device__ __forceinline__ void dstore(float* p, float v){
  __hip_atomic_store(p, v, __ATOMIC_RELAXED, __HIP_MEMORY_SCOPE_AGENT);
}
__device__ __forceinline__ int rload(const int* p){
  return __hip_atomic_load(p, __ATOMIC_RELAXED, __HIP_MEMORY_SCOPE_AGENT);
}
__device__ __forceinline__ void rstore(int* p, int v){
  __hip_atomic_store(p, v, __ATOMIC_RELAXED, __HIP_MEMORY_SCOPE_AGENT);
}
__device__ __forceinline__ void iadd(int* p){
  __hip_atomic_fetch_add(p, 1, __ATOMIC_RELAXED, __HIP_MEMORY_SCOPE_AGENT);
}
__device__ __forceinline__ float wredf(float v){
  #pragma unroll
  for (int m = 32; m; m >>= 1) v += __shfl_xor(v, m, 64);
  return v;
}
__device__ __forceinline__ float sigf(float z){ return 1.f/(1.f+__expf(-z)); }

__global__ __launch_bounds__(64) void bp_init(const float* __restrict__ x, float* wsf){
  const int t = blockIdx.x, tid = threadIdx.x;
  const float* xt = x + (size_t)t * INDIM;
  const float* xp = x + (size_t)(t > 0 ? t - 1 : 0) * INDIM;
  float sp = 0.f, nx = 0.f;
  #pragma unroll
  for (int e = 0; e < INDIM/64; e++){
    int i = tid + 64*e; float a = xt[i];
    nx += a*a; sp += a*xp[i];
  }
  sp = wredf(sp); nx = wredf(nx);
  if (tid == 0){ wsf[OFF_SDOT + t] = (t > 0) ? sp : 0.f; wsf[OFF_NORMX + t] = nx; }
  if (blockIdx.x == 0){
    int* wsi = (int*)wsf;
    for (int i = tid; i < 256; i += 64) wsi[OFF_ARRIVE + i] = 0;
    if (tid == 0) wsi[OFF_RELEASE] = 0;
    if (tid < 16){ wsi[OFF_PCNT + CSTR*tid] = 0; wsi[OFF_QCNT + CSTR*tid] = 0; }
    for (int i = tid; i < 2*NBANK*HID; i += 64) wsf[OFF_O1R + i] = 0.f;
    for (int i = tid; i < 2*16*64;     i += 64) wsf[OFF_P3 + i]  = 0.f;
    for (int i = tid; i < 2*16*8;      i += 64) wsf[OFF_ACC + i] = 0.f;
    __syncthreads();
    if (tid == 0){
      float* acc1 = wsf + OFF_ACC + 16*8;
      acc1[0] = 1.f; acc1[1] = 1.f; acc1[2] = 1.f; acc1[5] = 1.f;
    }
  }
}

__global__ __launch_bounds__(TPB) void bp_train(
    const float* __restrict__ xdat, const float* __restrict__ tgt,
    const float* __restrict__ w1g, const float* __restrict__ b1g,
    const float* __restrict__ w2g, const float* __restrict__ b2g,
    const float* __restrict__ w3g, const float* __restrict__ b3g,
    float* __restrict__ out, float* wsf)
{
  alignas(16) __shared__ float s1r[HID*CW];   // w1 ROW-major: [i][j]
  alignas(16) __shared__ float s2[CW*HID];    // w2 col-major: [j][i]
  __shared__ float s3[CW*OUTD];               // w3 rows
  alignas(16) __shared__ float a1b[2][HID];
  __shared__ float d1s[HID];
  __shared__ float b1s[HID];
  __shared__ float o1f[HID];
  __shared__ float d3b[2][OUTD];
  __shared__ float p3r[OUTD];
  __shared__ float b3s[OUTD];
  __shared__ float o2l[CW], d2l[CW], b2l[CW];
  __shared__ float a2b[2][CW];
  __shared__ float ascr[256];

  const int tid = threadIdx.x;
  const int wg  = blockIdx.x;
  int*   arrive  = (int*)wsf + OFF_ARRIVE;
  int*   release = (int*)wsf + OFF_RELEASE;
  int*   PCNT    = (int*)wsf + OFF_PCNT;
  int*   QCNT    = (int*)wsf + OFF_QCNT;
  float* U   = wsf + OFF_U;
  float* O1R = wsf + OFF_O1R;
  float* P3  = wsf + OFF_P3;
  float* AC  = wsf + OFF_ACC;
  float* SD  = wsf + OFF_SDOT;
  float* NX  = wsf + OFF_NORMX;
  const int bank  = wg & 15;
  const int obank = wg & (NBANK-1);
  const int wid   = tid >> 6;

  // ---- load owned slices + replicas, zero state ----
  {
    const float4 wv = *reinterpret_cast<const float4*>(&w1g[(size_t)tid*HID + wg*CW]);
    *reinterpret_cast<float4*>(&s1r[4*tid]) = wv;
  }
  for (int v = tid; v < CW*HID; v += TPB){
    int j = v & (CW-1); int i = v >> 2;
    s2[j*HID + i] = w2g[(size_t)i*HID + wg*CW + j];
  }
  if (tid < CW*OUTD){
    int i = tid >> 6; int k = tid & 63;
    s3[tid] = w3g[(size_t)(wg*CW + i)*OUTD + k];
  }
  b1s[tid] = b1g[tid]; d1s[tid] = 0.f; o1f[tid] = 0.f; a1b[1][tid] = 0.f;
  if (tid < OUTD){ b3s[tid] = b3g[tid]; d3b[1][tid] = 0.f; p3r[tid] = 0.f; }
  if (tid < CW){
    b2l[tid] = b2g[wg*CW + tid];
    o2l[tid] = 0.f; d2l[tid] = 0.f; a2b[0][tid] = 0.f; a2b[1][tid] = 0.f;
  }
  __syncthreads();

  // ---- publish u for step 0 ----
  {
    float xv = xdat[tid];
    float4 w = *reinterpret_cast<const float4*>(&s1r[4*tid]);
    float u0_ = wredf(xv*w.x), u1_ = wredf(xv*w.y);
    float u2_ = wredf(xv*w.z), u3_ = wredf(xv*w.w);
    if ((tid & 63) == 0){
      ascr[wid*4+0]=u0_; ascr[wid*4+1]=u1_; ascr[wid*4+2]=u2_; ascr[wid*4+3]=u3_;
    }
    __syncthreads();
    if (tid < CW){
      float s = 0.f;
      for (int w2_ = 0; w2_ < 16; w2_++) s += ascr[w2_*4 + tid];
      dstore(&U[wg*CW + tid], s);
    }
  }
  // initial full funnel barrier (once)
  {
    asm volatile("s_waitcnt vmcnt(0) lgkmcnt(0)" ::: "memory");
    __syncthreads();
    if (tid == 0) rstore(&arrive[wg], 1);
    if (wg == 0){
      if (tid < NWG){ while (rload(&arrive[tid]) < 1) __builtin_amdgcn_s_sleep(1); }
      __syncthreads();
      if (tid == 0) rstore(release, 1);
    }
    if (tid == 0){ while (rload(release) < 1) __builtin_amdgcn_s_sleep(1); }
    __syncthreads();
    asm volatile("" ::: "memory");
  }

  for (int t = 0; t <= NSTEP; t++){
    const int p = t & 1, qq = p ^ 1;
    float* a1c = a1b[p];  float* a1p = a1b[qq];
    float* a2c = a2b[p];  float* a2p = a2b[qq];
    float* d3c = d3b[p];  float* d3p = d3b[qq];

    // ================= Phase A =================
    if (tid < 112){
      int s = tid >> 4, b = tid & 15;
      ascr[128 + s*16 + b] = dload(&AC[(qq*16 + b)*8 + s]);
    }
    float u0 = dload(&U[tid]);
    float r0 = 0.f;
    #pragma unroll
    for (int b = 0; b < NBANK; b++)
      r0 += dload(&O1R[(qq*NBANK + b)*HID + tid]);
    float a1p0 = a1p[tid];
    float of0 = r0 * a1p0 * (1.f - a1p0);
    o1f[tid] = of0;

    // stage 2: per-wave partials
    {
      float v0 = d1s[tid]*of0;
      float v1 = of0*of0;
      float Ba = b1s[tid] - LR*of0;
      float v2 = Ba*Ba;
      float v3 = a1p0*a1p0;
      v0 = wredf(v0); v1 = wredf(v1); v2 = wredf(v2); v3 = wredf(v3);
      if ((tid & 63) == 0){
        ascr[0*16+wid]=v0; ascr[1*16+wid]=v1; ascr[2*16+wid]=v2; ascr[3*16+wid]=v3;
      }
      if (tid < 64){
        float d3v = d3p[tid];
        float v4 = d3v*d3v;
        float B3 = b3s[tid] - LR*d3v; float v5 = B3*B3;
        float v6 = d3v * p3r[tid];
        v4 = wredf(v4); v5 = wredf(v5); v6 = wredf(v6);
        if (tid == 0){ ascr[244]=v4; ascr[245]=v5; ascr[246]=v6; }
      }
    }
    __syncthreads();
    if (tid < 64){
      if (tid < 4){
        float s = 0.f;
        #pragma unroll
        for (int w = 0; w < 16; w++) s += ascr[tid*16 + w];
        ascr[240 + tid] = s;
      } else if (tid >= 8 && tid < 15){
        int s_ = tid - 8;
        float s = 0.f;
        #pragma unroll
        for (int b = 0; b < 16; b++) s += ascr[128 + s_*16 + b];
        ascr[248 + s_] = s;
      }
    }
    __syncthreads();
    float dd  = ascr[240], so  = ascr[241], sb  = ascr[242], sa1 = ascr[243];
    float sd3 = ascr[244], sb3 = ascr[245], dp3 = ascr[246];
    float m1p = ascr[248], m2p = ascr[249], m3p = ascr[250], dq  = ascr[251];
    float soq = ascr[252], sB2 = ascr[253], sa2 = ascr[254];

    float nxp = NX[t > 0 ? t - 1 : 0];
    float sdt = SD[t < NSTEP ? t : 0];
    float n1  = fmaxf(sqrtf(fmaxf(m1p - 2.f*LR*dd  + LR*LR*nxp*so,  0.f)), EPSN);
    float nb1 = fmaxf(sqrtf(sb),  EPSN);
    float n2  = fmaxf(sqrtf(fmaxf(m2p - 2.f*LR*dq  + LR*LR*sa1*soq, 0.f)), EPSN);
    float nb2 = fmaxf(sqrtf(sB2), EPSN);
    float n3  = fmaxf(sqrtf(fmaxf(m3p - 2.f*LR*dp3 + LR*LR*sa2*sd3, 0.f)), EPSN);
    float nb3 = fmaxf(sqrtf(sb3), EPSN);
    float rn1 = 1.f/n1, rnb1 = 1.f/nb1, rn2 = 1.f/n2, rnb2 = 1.f/nb2;
    float rn3 = 1.f/n3, rnb3 = 1.f/nb3;

    // stage 3
    {
      float B0 = (b1s[tid] - LR*of0)*rnb1; b1s[tid] = B0;
      float dn0 = (u0 - LR*of0*sdt)*rn1;   d1s[tid] = dn0;
      a1c[tid] = sigf(dn0 + B0);
    }
    __syncthreads();

    // stage 4: fused W2 update + matvec
    {
      int j = tid >> 8, l = tid & 255;
      float coef = LR * o2l[j];
      float4 w  = *reinterpret_cast<float4*>(&s2[j*HID + 4*l]);
      float4 ap = *reinterpret_cast<const float4*>(&a1p[4*l]);
      float4 ac = *reinterpret_cast<const float4*>(&a1c[4*l]);
      w.x = (w.x - coef*ap.x)*rn2;  w.y = (w.y - coef*ap.y)*rn2;
      w.z = (w.z - coef*ap.z)*rn2;  w.w = (w.w - coef*ap.w)*rn2;
      *reinterpret_cast<float4*>(&s2[j*HID + 4*l]) = w;
      float acc = ac.x*w.x + ac.y*w.y + ac.z*w.z + ac.w*w.w;
      float ms  = w.x*w.x + w.y*w.y + w.z*w.z + w.w*w.w;
      acc = wredf(acc); ms = wredf(ms);
      if ((tid & 63) == 0){ ascr[wid] = acc; ascr[16 + wid] = ms; }
    }
    __syncthreads();
    if (tid < CW){
      float d2 = ascr[4*tid] + ascr[4*tid+1] + ascr[4*tid+2] + ascr[4*tid+3];
      d2l[tid] = d2;
      float b2n = (b2l[tid] - LR*o2l[tid])*rnb2;
      b2l[tid] = b2n;
      a2c[tid] = sigf(d2 + b2n);
    }
    __syncthreads();
    if (tid == 0){
      float m2 = 0.f;
      #pragma unroll
      for (int w = 0; w < 16; w++) m2 += ascr[16 + w];
      unsafeAtomicAdd(&AC[(p*16 + bank)*8 + 1], m2);
      float s = 0.f;
      for (int j = 0; j < CW; j++){ float a = a2c[j]; s += a*a; }
      unsafeAtomicAdd(&AC[(p*16 + bank)*8 + 6], s);
    }

    // stage 5: fused W3 update + P3 publish (wave0 only)
    if (tid < OUTD){
      int k = tid;
      float d3k = d3p[k];
      float contrib = 0.f, m3s = 0.f;
      #pragma unroll
      for (int i = 0; i < CW; i++){
        float w = s3[i*OUTD + k];
        w = (w - LR*a2p[i]*d3k)*rn3;
        s3[i*OUTD + k] = w;
        contrib += a2c[i]*w;
        m3s += w*w;
      }
      unsafeAtomicAdd(&P3[(p*16 + bank)*OUTD + k], contrib);
      m3s = wredf(m3s);
      if (k == 0) unsafeAtomicAdd(&AC[(p*16 + bank)*8 + 2], m3s);
      b3s[k] = (b3s[k] - LR*d3k)*rnb3;
    }

    // ===== epilogue =====
    if (t == NSTEP){
      __syncthreads();
      const float* xl = xdat + (size_t)(NSTEP - 1)*INDIM;
      float xv = xl[tid];
      float c0 = LR*o1f[wg*CW+0], c1 = LR*o1f[wg*CW+1];
      float c2 = LR*o1f[wg*CW+2], c3 = LR*o1f[wg*CW+3];
      float4 w = *reinterpret_cast<const float4*>(&s1r[4*tid]);
      float4 ov;
      ov.x = (w.x - c0*xv)*rn1; ov.y = (w.y - c1*xv)*rn1;
      ov.z = (w.z - c2*xv)*rn1; ov.w = (w.w - c3*xv)*rn1;
      *reinterpret_cast<float4*>(&out[(size_t)tid*HID + wg*CW]) = ov;
      float4 o2v;
      o2v.x = s2[0*HID+tid]; o2v.y = s2[1*HID+tid];
      o2v.z = s2[2*HID+tid]; o2v.w = s2[3*HID+tid];
      *reinterpret_cast<float4*>(&out[(size_t)HID*HID + (size_t)tid*HID + wg*CW]) = o2v;
      if (tid < OUTD){
        #pragma unroll
        for (int i = 0; i < CW; i++)
          out[(size_t)2*HID*HID + (size_t)(wg*CW + i)*OUTD + tid] = s3[i*OUTD + tid];
      }
      break;
    }

    // ---- P-arrive: all P-side publishes are wave0's atomics ----
    if (wid == 0){
      asm volatile("s_waitcnt vmcnt(0) lgkmcnt(0)" ::: "memory");
      if (tid == 0) iadd(&PCNT[CSTR*bank]);
    }

    // ---- shadow (WG-local): fused W1 update + u_{t+1} partials + m1 ----
    float u_pub = 0.f;
    {
      const float* xp_ = xdat + (size_t)(t > 0 ? t - 1 : 0)*INDIM;
      const float* xn_ = xdat + (size_t)(t + 1 < NSTEP ? t + 1 : NSTEP - 1)*INDIM;
      float xpv = xp_[tid], xnv = xn_[tid];
      float c0 = LR*o1f[wg*CW+0], c1 = LR*o1f[wg*CW+1];
      float c2 = LR*o1f[wg*CW+2], c3 = LR*o1f[wg*CW+3];
      float4 w = *reinterpret_cast<float4*>(&s1r[4*tid]);
      w.x = (w.x - c0*xpv)*rn1; w.y = (w.y - c1*xpv)*rn1;
      w.z = (w.z - c2*xpv)*rn1; w.w = (w.w - c3*xpv)*rn1;
      *reinterpret_cast<float4*>(&s1r[4*tid]) = w;
      float m1s = w.x*w.x + w.y*w.y + w.z*w.z + w.w*w.w;
      float u0_ = wredf(xnv*w.x), u1_ = wredf(xnv*w.y);
      float u2_ = wredf(xnv*w.z), u3_ = wredf(xnv*w.w);
      m1s = wredf(m1s);
      if ((tid & 63) == 0){
        ascr[wid*4+0]=u0_; ascr[wid*4+1]=u1_; ascr[wid*4+2]=u2_; ascr[wid*4+3]=u3_;
        ascr[64 + wid] = m1s;
      }
      __syncthreads();
      if (tid < CW){
        float s = 0.f;
        #pragma unroll
        for (int w2_ = 0; w2_ < 16; w2_++) s += ascr[w2_*4 + tid];
        u_pub = s;
      }
      if (tid == 0){
        float m1 = 0.f;
        #pragma unroll
        for (int w2_ = 0; w2_ < 16; w2_++) m1 += ascr[64 + w2_];
        unsafeAtomicAdd(&AC[(p*16 + bank)*8 + 0], m1);
      }
    }

    // ---- P-wait: poll 16 padded producer counters (one line each) ----
    {
      const int ptgt = 16*(t+1);
      if (tid < 16){
        while (rload(&PCNT[CSTR*tid]) < ptgt) __builtin_amdgcn_s_sleep(1);
      }
      __syncthreads();
      asm volatile("" ::: "memory");
    }

    // ================= Phase B =================
    if (tid < CW) dstore(&U[wg*CW + tid], u_pub);   // safe: all WGs past A stage1
    if (tid < OUTD){
      float s = 0.f;
      for (int b = 0; b < 16; b++) s += dload(&P3[(p*16 + b)*OUTD + tid]);
      p3r[tid] = s;
      float a3 = sigf(s + b3s[tid]);
      float e3 = __expf(-a3);
      float es = wredf(e3);
      float net = e3 / es;
      float tv = tgt[(size_t)t*OUTD + tid];
      d3c[tid] = (tv - net) * a3 * (1.f - a3);
    }
    __syncthreads();
    if (tid < CW*OUTD){
      int i = tid >> 6, k = tid & 63;
      float v = wredf(s3[i*OUTD + k] * d3c[k]);
      if (k == 0){ float a2v = a2c[i]; o2l[i] = v * a2v * (1.f - a2v); }
    }
    __syncthreads();
    if (tid == 0){
      float dd2 = 0.f, so2 = 0.f, sB2n = 0.f;
      for (int j = 0; j < CW; j++){
        float ov = o2l[j];
        dd2 += d2l[j]*ov; so2 += ov*ov;
        float B = b2l[j] - LR*ov; sB2n += B*B;
      }
      unsafeAtomicAdd(&AC[(p*16 + bank)*8 + 3], dd2);
      unsafeAtomicAdd(&AC[(p*16 + bank)*8 + 4], so2);
      unsafeAtomicAdd(&AC[(p*16 + bank)*8 + 5], sB2n);
    }
    // o1 banked partial over owned columns
    {
      float q0 = s2[0*HID+tid]*o2l[0] + s2[1*HID+tid]*o2l[1]
               + s2[2*HID+tid]*o2l[2] + s2[3*HID+tid]*o2l[3];
      unsafeAtomicAdd(&O1R[(p*NBANK + obank)*HID + tid], q0);
    }
    // zero next-parity accumulators
    if (wg < NBANK) dstore(&O1R[(qq*NBANK + wg)*HID + tid], 0.f);
    if (wg < 16){
      if (tid < OUTD) dstore(&P3[(qq*16 + wg)*OUTD + tid], 0.f);
      if (tid < 8)    dstore(&AC[(qq*16 + wg)*8 + tid], 0.f);
    }
    // ---- Q-arrive: block-wide drain, then bump padded counter ----
    asm volatile("s_waitcnt vmcnt(0) lgkmcnt(0)" ::: "memory");
    __syncthreads();
    if (tid == 0) iadd(&QCNT[CSTR*bank]);
    // ---- Q-wait ----
    {
      const int qtgt = 16*(t+1);
      if (tid < 16){
        while (rload(&QCNT[CSTR*tid]) < qtgt) __builtin_amdgcn_s_sleep(1);
      }
      __syncthreads();
      asm volatile("" ::: "memory");
    }
  }
}

extern "C" void kernel_launch(void* const* d_in, const int* in_sizes, int n_in,
                              void* d_out, int out_size, void* d_ws, size_t ws_size,
                              hipStream_t stream){
  const float* x  = (const float*)d_in[0];
  const float* tg = (const float*)d_in[1];
  const float* w1 = (const float*)d_in[2];
  const float* b1 = (const float*)d_in[3];
  const float* w2 = (const float*)d_in[4];
  const float* b2 = (const float*)d_in[5];
  const float* w3 = (const float*)d_in[6];
  const float* b3 = (const float*)d_in[7];
  float* out = (float*)d_out;
  float* wsf = (float*)d_ws;
  hipLaunchKernelGGL(bp_init,  dim3(NSTEP), dim3(64),  0, stream, x, wsf);
  hipLaunchKernelGGL(bp_train, dim3(NWG),   dim3(TPB), 0, stream,
                     x, tg, w1, b1, w2, b2, w3, b3, out, wsf);
}